// Round 2
// baseline (4537.074 us; speedup 1.0000x reference)
//
#include <hip/hip_runtime.h>
#include <hip/hip_bf16.h>

typedef __attribute__((ext_vector_type(8))) short bh8;   // 8 x bf16 (4 VGPRs)
typedef __attribute__((ext_vector_type(4))) float f4;    // MFMA accumulator

static constexpr int T_STEPS = 128;
static constexpr int BTOT    = 2048;
static constexpr int HD      = 256;
static constexpr int NG      = 768;   // 3*H
static constexpr int LOUT    = 100;
static constexpr int LDS_STRIDE = 264; // 256 + 8 pad (bf16 elems) -> conflict-free ds_read_b128

__device__ __forceinline__ short f2bf(float f){
  unsigned u = __builtin_bit_cast(unsigned, f);
  unsigned r = (u + 0x7FFFu + ((u >> 16) & 1u)) >> 16;   // RNE
  return (short)(unsigned short)r;
}

__device__ __forceinline__ f4 mfma16(bh8 a, bh8 b, f4 c){
  return __builtin_amdgcn_mfma_f32_16x16x32_bf16(a, b, c, 0, 0, 0);
}

__device__ __forceinline__ float sigm(float x){
  return __builtin_amdgcn_rcpf(1.f + __expf(-x));
}
__device__ __forceinline__ float tanh_f(float x){
  return 1.f - 2.f*__builtin_amdgcn_rcpf(1.f + __expf(2.f*x));
}

// ---------------- prep: E0 = emb @ w_ih0^T + b_ih0  ([64][768] f32) ----------------
__global__ void e0_kernel(const float* __restrict__ emb, const float* __restrict__ w_ih0,
                          const float* __restrict__ b_ih0, float* __restrict__ E0)
{
  int tid = blockIdx.x*blockDim.x + threadIdx.x;
  if (tid >= 64*NG) return;
  int v = tid / NG, n = tid % NG;
  const float4* er = (const float4*)(emb + (size_t)v*HD);
  const float4* wr = (const float4*)(w_ih0 + (size_t)n*HD);
  float s = 0.f;
#pragma unroll 4
  for (int k=0;k<HD/4;++k){
    float4 a = er[k], b = wr[k];
    s += a.x*b.x + a.y*b.y + a.z*b.z + a.w*b.w;
  }
  E0[tid] = s + b_ih0[n];
}

// ---------------- prep: pack all weights into B-fragment-linear bf16 tiles ----------------
// (unchanged from round 1 — verified correct)
__global__ void pack_kernel(const float* __restrict__ w_hh0, const float* __restrict__ w_ih1,
                            const float* __restrict__ w_hh1, const float* __restrict__ w1,
                            const float* __restrict__ w2, short* __restrict__ pack)
{
  int tid = blockIdx.x*blockDim.x + threadIdx.x;
  if (tid >= 1336*64) return;
  int t = tid >> 6, lane = tid & 63;
  int l15 = lane & 15, lq = lane >> 4;
  const float* src = nullptr;
  bool zero = false;
  if (t < 384){
    int w = t/48, rem = t%48, i = rem/8, kt = rem%8;
    int n = (i>>1)*256 + w*32 + (i&1)*16 + l15;
    src = w_hh0 + (size_t)n*HD + kt*32 + lq*8;
  } else if (t < 1152){
    int tt = t - 384, w = tt/96, rem = tt%96, i = rem/16, kt = rem%16;
    int n = (i>>1)*256 + w*32 + (i&1)*16 + l15;
    src = (kt < 8) ? (w_ih1 + (size_t)n*HD + kt*32 + lq*8)
                   : (w_hh1 + (size_t)n*HD + (kt-8)*32 + lq*8);
  } else if (t < 1280){
    int tt = t - 1152, w = tt/16, rem = tt%16, ntt = rem/8, kt = rem%8;
    int n = w*32 + ntt*16 + l15;
    src = w1 + (size_t)n*HD + kt*32 + lq*8;
  } else {
    int tt = t - 1280, ntt = tt/8, kt = tt%8;
    int n = ntt*16 + l15;
    if (n < LOUT) src = w2 + (size_t)n*HD + kt*32 + lq*8;
    else zero = true;
  }
  bh8 o;
#pragma unroll
  for (int e=0;e<8;++e) o[e] = zero ? (short)0 : f2bf(src[e]);
  ((bh8*)pack)[tid] = o;
}

// ---------------- main: fused 2-layer GRU scan + head, 1 wg = 32 batch rows ----------------
// M=32 via two 16-row A tiles per wave -> each B fragment feeds 2 MFMAs,
// total weight traffic halves vs 16-row wgs. 256-VGPR budget, no spills.
__global__ __launch_bounds__(512, 1)
void rnn_main(const int* __restrict__ tokens, const int* __restrict__ lens,
              const float* __restrict__ E0, const short* __restrict__ pack,
              const float* __restrict__ b_hh0, const float* __restrict__ b_ih1,
              const float* __restrict__ b_hh1, const float* __restrict__ b1,
              const float* __restrict__ b2, float* __restrict__ out)
{
  const int tid  = threadIdx.x;
  const int wid  = tid >> 6;      // wave 0..7, owns hidden dims [32*wid, 32*wid+32)
  const int lane = tid & 63;
  const int l15  = lane & 15;
  const int lq   = lane >> 4;
  const int b0   = blockIdx.x * 32;

  __shared__ __align__(16) short s0_lds[32*LDS_STRIDE]; // layer0 state (bf16)
  __shared__ __align__(16) short s1_lds[32*LDS_STRIDE]; // layer1 state
  __shared__ float bias0[NG], biasI1[NG], biasH1[NG], b1s[HD], b2s[112];

  for (int i = tid; i < 32*LDS_STRIDE; i += 512){ s0_lds[i] = 0; s1_lds[i] = 0; }
  for (int i = tid; i < NG; i += 512){ bias0[i] = b_hh0[i]; biasI1[i] = b_ih1[i]; biasH1[i] = b_hh1[i]; }
  if (tid < HD)  b1s[tid] = b1[tid];
  if (tid < 112) b2s[tid] = (tid < LOUT) ? b2[tid] : 0.f;

  int mylens[2][4];
#pragma unroll
  for (int rt=0;rt<2;++rt)
#pragma unroll
    for (int r=0;r<4;++r) mylens[rt][r] = lens[b0 + rt*16 + lq*4 + r];

  float h0s[2][2][4], h1s[2][2][4], outf[2][2][4];   // [rt][nt][r4]
#pragma unroll
  for (int rt=0;rt<2;++rt)
#pragma unroll
    for (int nt=0;nt<2;++nt)
#pragma unroll
      for (int r=0;r<4;++r){ h0s[rt][nt][r]=0.f; h1s[rt][nt][r]=0.f; outf[rt][nt][r]=0.f; }

  const bh8* __restrict__ packL0 = (const bh8*)pack + (size_t)(       wid*48)*64 + lane;
  const bh8* __restrict__ packL1 = (const bh8*)pack + (size_t)( 384 + wid*96)*64 + lane;
  const bh8* __restrict__ packW1 = (const bh8*)pack + (size_t)(1152 + wid*16)*64 + lane;
  const bh8* __restrict__ packW2 = (const bh8*)pack + (size_t)(1280 + wid*8 )*64 + lane;

  const short* s0p = &s0_lds[l15*LDS_STRIDE + lq*8];  // A-frag base: row l15, k0 = lq*8
  const short* s1p = &s1_lds[l15*LDS_STRIDE + lq*8];
  constexpr int RT1 = 16*LDS_STRIDE;                  // second row-tile offset (elems)

  const f4 zf = {0.f, 0.f, 0.f, 0.f};

  __syncthreads();

#pragma unroll 1
  for (int t = 0; t < T_STEPS; ++t){
    int tokr[2][4];
#pragma unroll
    for (int rt=0;rt<2;++rt)
#pragma unroll
      for (int r=0;r<4;++r) tokr[rt][r] = tokens[t*BTOT + b0 + rt*16 + lq*4 + r];

    // ---- layer 0 GEMM: gh0 = s0 @ w_hh0^T  (K=256), both row tiles ----
    f4 acc0[6][2];
#pragma unroll
    for (int i=0;i<6;++i){ acc0[i][0]=zf; acc0[i][1]=zf; }
#pragma unroll
    for (int kt=0;kt<8;++kt){
      bh8 a0 = *(const bh8*)(s0p + kt*32);
      bh8 a1 = *(const bh8*)(s0p + RT1 + kt*32);
#pragma unroll
      for (int i=0;i<6;++i){
        bh8 b = packL0[(i*8+kt)*64];
        acc0[i][0] = mfma16(a0, b, acc0[i][0]);
        acc0[i][1] = mfma16(a1, b, acc0[i][1]);
      }
    }
    __syncthreads();  // A: all waves done reading s0_lds

    // ---- layer 0 epilogue ----
#pragma unroll
    for (int rt=0;rt<2;++rt){
#pragma unroll
      for (int nt=0;nt<2;++nt){
        const int jb = wid*32 + nt*16 + l15;
        const float bhr = bias0[jb], bhz = bias0[256+jb], bhn = bias0[512+jb];
#pragma unroll
        for (int r4=0;r4<4;++r4){
          const int brow = rt*16 + lq*4 + r4;
          const float* e0p = E0 + (size_t)tokr[rt][r4]*NG + jb;
          const float gir = e0p[0], giz = e0p[256], gin = e0p[512];
          const float rg = sigm(acc0[0+nt][rt][r4] + bhr + gir);
          const float zg = sigm(acc0[2+nt][rt][r4] + bhz + giz);
          const float ng = tanh_f(gin + rg*(acc0[4+nt][rt][r4] + bhn));
          float h = h0s[rt][nt][r4];
          h = ng + zg*(h - ng);
          h0s[rt][nt][r4] = h;
          s0_lds[brow*LDS_STRIDE + jb] = f2bf(h);
        }
      }
    }
    __syncthreads();  // B: s0_lds now holds s0_t

    // ---- layer 1 GEMM: A = [s0_t | s1_{t-1}], K=512 ----
    f4 ar_[2][2], az_[2][2], ani[2][2], anh[2][2];   // [nt][rt]
#pragma unroll
    for (int nt=0;nt<2;++nt){
      ar_[nt][0]=zf; ar_[nt][1]=zf; az_[nt][0]=zf; az_[nt][1]=zf;
      ani[nt][0]=zf; ani[nt][1]=zf; anh[nt][0]=zf; anh[nt][1]=zf;
    }
#pragma unroll
    for (int kt=0;kt<16;++kt){
      const short* abase = (kt < 8) ? (s0p + kt*32) : (s1p + (kt-8)*32);
      bh8 a0 = *(const bh8*)abase;
      bh8 a1 = *(const bh8*)(abase + RT1);
#pragma unroll
      for (int nt=0;nt<2;++nt){
        bh8 br = packL1[((0+nt)*16+kt)*64];
        bh8 bz = packL1[((2+nt)*16+kt)*64];
        bh8 bn = packL1[((4+nt)*16+kt)*64];
        ar_[nt][0] = mfma16(a0, br, ar_[nt][0]);
        ar_[nt][1] = mfma16(a1, br, ar_[nt][1]);
        az_[nt][0] = mfma16(a0, bz, az_[nt][0]);
        az_[nt][1] = mfma16(a1, bz, az_[nt][1]);
        if (kt < 8){
          ani[nt][0] = mfma16(a0, bn, ani[nt][0]);
          ani[nt][1] = mfma16(a1, bn, ani[nt][1]);
        } else {
          anh[nt][0] = mfma16(a0, bn, anh[nt][0]);
          anh[nt][1] = mfma16(a1, bn, anh[nt][1]);
        }
      }
    }
    __syncthreads();  // C: all waves done reading s0_lds/s1_lds

    // ---- layer 1 epilogue + output capture ----
#pragma unroll
    for (int rt=0;rt<2;++rt){
#pragma unroll
      for (int nt=0;nt<2;++nt){
        const int jb = wid*32 + nt*16 + l15;
        const float bir = biasI1[jb],     bhr = biasH1[jb];
        const float biz = biasI1[256+jb], bhz = biasH1[256+jb];
        const float bin = biasI1[512+jb], bhn = biasH1[512+jb];
#pragma unroll
        for (int r4=0;r4<4;++r4){
          const int brow = rt*16 + lq*4 + r4;
          const float rg = sigm(ar_[nt][rt][r4] + bir + bhr);
          const float zg = sigm(az_[nt][rt][r4] + biz + bhz);
          const float ng = tanh_f((ani[nt][rt][r4] + bin) + rg*(anh[nt][rt][r4] + bhn));
          float h = h1s[rt][nt][r4];
          h = ng + zg*(h - ng);
          h1s[rt][nt][r4] = h;
          if (mylens[rt][r4] == t) outf[rt][nt][r4] = h;
          s1_lds[brow*LDS_STRIDE + jb] = f2bf(h);
        }
      }
    }
    // no barrier: next iteration's barriers A/B order s1 writes vs reads
  }

  // ---- head: z = LeakyReLU(out_t @ w1^T + b1); enc = z @ w2^T + b2 ----
#pragma unroll
  for (int rt=0;rt<2;++rt)
#pragma unroll
    for (int nt=0;nt<2;++nt){
      const int jb = wid*32 + nt*16 + l15;
#pragma unroll
      for (int r4=0;r4<4;++r4)
        s0_lds[(rt*16+lq*4+r4)*LDS_STRIDE + jb] = f2bf(outf[rt][nt][r4]);
    }
  __syncthreads();

  {
    f4 az[2][2]; az[0][0]=zf; az[0][1]=zf; az[1][0]=zf; az[1][1]=zf;
#pragma unroll
    for (int kt=0;kt<8;++kt){
      bh8 a0 = *(const bh8*)(s0p + kt*32);
      bh8 a1 = *(const bh8*)(s0p + RT1 + kt*32);
#pragma unroll
      for (int nt=0;nt<2;++nt){
        bh8 b = packW1[(nt*8+kt)*64];
        az[nt][0] = mfma16(a0, b, az[nt][0]);
        az[nt][1] = mfma16(a1, b, az[nt][1]);
      }
    }
#pragma unroll
    for (int rt=0;rt<2;++rt)
#pragma unroll
      for (int nt=0;nt<2;++nt){
        const int jb = wid*32 + nt*16 + l15;
#pragma unroll
        for (int r4=0;r4<4;++r4){
          float v = az[nt][rt][r4] + b1s[jb];
          v = (v >= 0.f) ? v : 0.01f*v;     // LeakyReLU
          s1_lds[(rt*16+lq*4+r4)*LDS_STRIDE + jb] = f2bf(v);
        }
      }
  }
  __syncthreads();

  if (wid < 7){
    f4 acc2[2]; acc2[0]=zf; acc2[1]=zf;
#pragma unroll
    for (int kt=0;kt<8;++kt){
      bh8 a0 = *(const bh8*)(s1p + kt*32);
      bh8 a1 = *(const bh8*)(s1p + RT1 + kt*32);
      bh8 b = packW2[kt*64];
      acc2[0] = mfma16(a0, b, acc2[0]);
      acc2[1] = mfma16(a1, b, acc2[1]);
    }
    const int n2 = wid*16 + l15;
    if (n2 < LOUT){
#pragma unroll
      for (int rt=0;rt<2;++rt)
#pragma unroll
        for (int r4=0;r4<4;++r4)
          out[(size_t)(b0 + rt*16 + lq*4 + r4)*LOUT + n2] = acc2[rt][r4] + b2s[n2];
    }
  }
}

extern "C" void kernel_launch(void* const* d_in, const int* in_sizes, int n_in,
                              void* d_out, int out_size, void* d_ws, size_t ws_size,
                              hipStream_t stream)
{
  const int*   tokens = (const int*)  d_in[0];
  const int*   lens   = (const int*)  d_in[1];
  const float* emb    = (const float*)d_in[2];
  const float* w_ih0  = (const float*)d_in[3];
  const float* w_hh0  = (const float*)d_in[4];
  const float* b_ih0  = (const float*)d_in[5];
  const float* b_hh0  = (const float*)d_in[6];
  const float* w_ih1  = (const float*)d_in[7];
  const float* w_hh1  = (const float*)d_in[8];
  const float* b_ih1  = (const float*)d_in[9];
  const float* b_hh1  = (const float*)d_in[10];
  const float* w1     = (const float*)d_in[11];
  const float* b1     = (const float*)d_in[12];
  const float* w2     = (const float*)d_in[13];
  const float* b2     = (const float*)d_in[14];

  float* E0   = (float*)d_ws;                                  // 64*768*4 = 196608 B
  short* pack = (short*)((char*)d_ws + 64*NG*sizeof(float));   // 1336 KiB packed bf16 tiles

  e0_kernel  <<<(64*NG + 255)/256,   256, 0, stream>>>(emb, w_ih0, b_ih0, E0);
  pack_kernel<<<(1336*64 + 255)/256, 256, 0, stream>>>(w_hh0, w_ih1, w_hh1, w1, w2, pack);
  rnn_main   <<<64, 512, 0, stream>>>(tokens, lens, E0, pack,
                                      b_hh0, b_ih1, b_hh1, b1, b2, (float*)d_out);
}

// Round 3
// 4265.424 us; speedup vs baseline: 1.0637x; 1.0637x over previous
//
#include <hip/hip_runtime.h>
#include <hip/hip_bf16.h>

typedef __attribute__((ext_vector_type(8))) short bh8;   // 8 x bf16 (4 VGPRs)
typedef __attribute__((ext_vector_type(4))) float f4;    // MFMA accumulator

static constexpr int T_STEPS = 128;
static constexpr int BTOT    = 2048;
static constexpr int HD      = 256;
static constexpr int NG      = 768;   // 3*H
static constexpr int LOUT    = 100;
static constexpr int LDS_STRIDE = 264; // 256 + 8 pad (bf16) -> conflict-free ds_read_b128

__device__ __forceinline__ short f2bf(float f){
  unsigned u = __builtin_bit_cast(unsigned, f);
  unsigned r = (u + 0x7FFFu + ((u >> 16) & 1u)) >> 16;   // RNE
  return (short)(unsigned short)r;
}
__device__ __forceinline__ float bf2f(short s){
  unsigned u = ((unsigned)(unsigned short)s) << 16;
  return __builtin_bit_cast(float, u);
}

__device__ __forceinline__ f4 mfma16(bh8 a, bh8 b, f4 c){
  return __builtin_amdgcn_mfma_f32_16x16x32_bf16(a, b, c, 0, 0, 0);
}

__device__ __forceinline__ float sigm(float x){
  return __builtin_amdgcn_rcpf(1.f + __expf(-x));
}
__device__ __forceinline__ float tanh_f(float x){
  return 1.f - 2.f*__builtin_amdgcn_rcpf(1.f + __expf(2.f*x));
}

// ---------------- prep: E0 = emb @ w_ih0^T + b_ih0  ([64][768] f32) ----------------
__global__ void e0_kernel(const float* __restrict__ emb, const float* __restrict__ w_ih0,
                          const float* __restrict__ b_ih0, float* __restrict__ E0)
{
  int tid = blockIdx.x*blockDim.x + threadIdx.x;
  if (tid >= 64*NG) return;
  int v = tid / NG, n = tid % NG;
  const float4* er = (const float4*)(emb + (size_t)v*HD);
  const float4* wr = (const float4*)(w_ih0 + (size_t)n*HD);
  float s = 0.f;
#pragma unroll 4
  for (int k=0;k<HD/4;++k){
    float4 a = er[k], b = wr[k];
    s += a.x*b.x + a.y*b.y + a.z*b.z + a.w*b.w;
  }
  E0[tid] = s + b_ih0[n];
}

// ---------------- prep: pack all weights into B-fragment-linear bf16 tiles ----------------
// (verified in rounds 1-2)
__global__ void pack_kernel(const float* __restrict__ w_hh0, const float* __restrict__ w_ih1,
                            const float* __restrict__ w_hh1, const float* __restrict__ w1,
                            const float* __restrict__ w2, short* __restrict__ pack)
{
  int tid = blockIdx.x*blockDim.x + threadIdx.x;
  if (tid >= 1336*64) return;
  int t = tid >> 6, lane = tid & 63;
  int l15 = lane & 15, lq = lane >> 4;
  const float* src = nullptr;
  bool zero = false;
  if (t < 384){
    int w = t/48, rem = t%48, i = rem/8, kt = rem%8;
    int n = (i>>1)*256 + w*32 + (i&1)*16 + l15;
    src = w_hh0 + (size_t)n*HD + kt*32 + lq*8;
  } else if (t < 1152){
    int tt = t - 384, w = tt/96, rem = tt%96, i = rem/16, kt = rem%16;
    int n = (i>>1)*256 + w*32 + (i&1)*16 + l15;
    src = (kt < 8) ? (w_ih1 + (size_t)n*HD + kt*32 + lq*8)
                   : (w_hh1 + (size_t)n*HD + (kt-8)*32 + lq*8);
  } else if (t < 1280){
    int tt = t - 1152, w = tt/16, rem = tt%16, ntt = rem/8, kt = rem%8;
    int n = w*32 + ntt*16 + l15;
    src = w1 + (size_t)n*HD + kt*32 + lq*8;
  } else {
    int tt = t - 1280, ntt = tt/8, kt = tt%8;
    int n = ntt*16 + l15;
    if (n < LOUT) src = w2 + (size_t)n*HD + kt*32 + lq*8;
    else zero = true;
  }
  bh8 o;
#pragma unroll
  for (int e=0;e<8;++e) o[e] = zero ? (short)0 : f2bf(src[e]);
  ((bh8*)pack)[tid] = o;
}

// ---------------- main: fused 2-layer GRU scan + head, 1 wg = 32 batch rows ----------------
// Pressure-minimized: L1 GEMM is nt-outer (8 live acc f4), per-nt epilogue,
// s1 double-buffered in LDS (kills 3rd barrier), h0 carried as bf16 in LDS.
__global__ __launch_bounds__(512, 1)
void rnn_main(const int* __restrict__ tokens, const int* __restrict__ lens,
              const float* __restrict__ E0, const short* __restrict__ pack,
              const float* __restrict__ b_hh0, const float* __restrict__ b_ih1,
              const float* __restrict__ b_hh1, const float* __restrict__ b1,
              const float* __restrict__ b2, float* __restrict__ out)
{
  const int tid  = threadIdx.x;
  const int wid  = tid >> 6;      // wave 0..7, owns gate-cols [32*wid, 32*wid+32)
  const int lane = tid & 63;
  const int l15  = lane & 15;
  const int lq   = lane >> 4;
  const int b0   = blockIdx.x * 32;

  __shared__ __align__(16) short s0_lds[32*LDS_STRIDE];      // layer0 state (bf16)
  __shared__ __align__(16) short s1_lds[2][32*LDS_STRIDE];   // layer1 state, dbl-buffered
  __shared__ float bias0[NG], biasI1[NG], biasH1[NG], b1s[HD], b2s[112];

  for (int i = tid; i < 32*LDS_STRIDE; i += 512){
    s0_lds[i] = 0; s1_lds[0][i] = 0; s1_lds[1][i] = 0;
  }
  for (int i = tid; i < NG; i += 512){ bias0[i] = b_hh0[i]; biasI1[i] = b_ih1[i]; biasH1[i] = b_hh1[i]; }
  if (tid < HD)  b1s[tid] = b1[tid];
  if (tid < 112) b2s[tid] = (tid < LOUT) ? b2[tid] : 0.f;

  int mylens[2][4];
#pragma unroll
  for (int rt=0;rt<2;++rt)
#pragma unroll
    for (int r=0;r<4;++r) mylens[rt][r] = lens[b0 + rt*16 + lq*4 + r];

  float h1s[2][2][4], outf[2][2][4];   // [rt][nt][r4]
#pragma unroll
  for (int rt=0;rt<2;++rt)
#pragma unroll
    for (int nt=0;nt<2;++nt)
#pragma unroll
      for (int r=0;r<4;++r){ h1s[rt][nt][r]=0.f; outf[rt][nt][r]=0.f; }

  const bh8* __restrict__ packL0 = (const bh8*)pack + (size_t)(       wid*48)*64 + lane;
  const bh8* __restrict__ packL1 = (const bh8*)pack + (size_t)( 384 + wid*96)*64 + lane;
  const bh8* __restrict__ packW1 = (const bh8*)pack + (size_t)(1152 + wid*16)*64 + lane;
  const bh8* __restrict__ packW2 = (const bh8*)pack + (size_t)(1280 + wid*8 )*64 + lane;

  const int afrag = l15*LDS_STRIDE + lq*8;     // A-frag base offset: row l15, k0 = lq*8
  const short* s0p = &s0_lds[afrag];
  constexpr int RT1 = 16*LDS_STRIDE;           // second row-tile offset (elems)

  const f4 zf = {0.f, 0.f, 0.f, 0.f};

  __syncthreads();

#pragma unroll 1
  for (int t = 0; t < T_STEPS; ++t){
    int tokr[2][4];
#pragma unroll
    for (int rt=0;rt<2;++rt)
#pragma unroll
      for (int r=0;r<4;++r) tokr[rt][r] = tokens[t*BTOT + b0 + rt*16 + lq*4 + r];

    // ---- layer 0 GEMM: gh0 = s0 @ w_hh0^T  (K=256), both row tiles ----
    f4 acc0[6][2];
#pragma unroll
    for (int i=0;i<6;++i){ acc0[i][0]=zf; acc0[i][1]=zf; }
#pragma unroll
    for (int kt=0;kt<8;++kt){
      bh8 a0 = *(const bh8*)(s0p + kt*32);
      bh8 a1 = *(const bh8*)(s0p + RT1 + kt*32);
#pragma unroll
      for (int i=0;i<6;++i){
        bh8 b = packL0[(i*8+kt)*64];
        acc0[i][0] = mfma16(a0, b, acc0[i][0]);
        acc0[i][1] = mfma16(a1, b, acc0[i][1]);
      }
    }
    __syncthreads();  // A: all waves done reading s0_lds (and s1 writes of t-1 visible)

    // ---- layer 0 epilogue: h0 carried as bf16 in LDS ----
#pragma unroll
    for (int rt=0;rt<2;++rt){
#pragma unroll
      for (int nt=0;nt<2;++nt){
        const int jb = wid*32 + nt*16 + l15;
        const float bhr = bias0[jb], bhz = bias0[256+jb], bhn = bias0[512+jb];
#pragma unroll
        for (int r4=0;r4<4;++r4){
          const int brow = rt*16 + lq*4 + r4;
          const float* e0p = E0 + (size_t)tokr[rt][r4]*NG + jb;
          const float gir = e0p[0], giz = e0p[256], gin = e0p[512];
          const float rg = sigm(acc0[0+nt][rt][r4] + bhr + gir);
          const float zg = sigm(acc0[2+nt][rt][r4] + bhz + giz);
          const float ng = tanh_f(gin + rg*(acc0[4+nt][rt][r4] + bhn));
          const float ho = bf2f(s0_lds[brow*LDS_STRIDE + jb]);   // h0_{t-1}, thread-private loc
          const float h = ng + zg*(ho - ng);
          s0_lds[brow*LDS_STRIDE + jb] = f2bf(h);
        }
      }
    }
    __syncthreads();  // B: s0_lds now holds s0_t

    // ---- layer 1: A = [s0_t | s1_{t-1}], K=512; nt-outer, per-nt epilogue ----
    const short* s1r = &s1_lds[t & 1][afrag];          // read buffer (h1_{t-1})
    short*       s1w = &s1_lds[(t + 1) & 1][0];        // write buffer (h1_t)
#pragma unroll
    for (int nt=0;nt<2;++nt){
      f4 ar_[2], az_[2], ani[2], anh[2];
      ar_[0]=zf; ar_[1]=zf; az_[0]=zf; az_[1]=zf;
      ani[0]=zf; ani[1]=zf; anh[0]=zf; anh[1]=zf;
#pragma unroll
      for (int kt=0;kt<16;++kt){
        const short* abase = (kt < 8) ? (s0p + kt*32) : (s1r + (kt-8)*32);
        bh8 a0 = *(const bh8*)abase;
        bh8 a1 = *(const bh8*)(abase + RT1);
        bh8 br = packL1[((0+nt)*16+kt)*64];
        bh8 bz = packL1[((2+nt)*16+kt)*64];
        bh8 bn = packL1[((4+nt)*16+kt)*64];
        ar_[0] = mfma16(a0, br, ar_[0]);
        ar_[1] = mfma16(a1, br, ar_[1]);
        az_[0] = mfma16(a0, bz, az_[0]);
        az_[1] = mfma16(a1, bz, az_[1]);
        if (kt < 8){
          ani[0] = mfma16(a0, bn, ani[0]);
          ani[1] = mfma16(a1, bn, ani[1]);
        } else {
          anh[0] = mfma16(a0, bn, anh[0]);
          anh[1] = mfma16(a1, bn, anh[1]);
        }
      }
      // per-nt epilogue (writes go to the OTHER s1 buffer -> no barrier needed)
      const int jb = wid*32 + nt*16 + l15;
      const float bir = biasI1[jb],     bhr = biasH1[jb];
      const float biz = biasI1[256+jb], bhz = biasH1[256+jb];
      const float bin = biasI1[512+jb], bhn = biasH1[512+jb];
#pragma unroll
      for (int rt=0;rt<2;++rt){
#pragma unroll
        for (int r4=0;r4<4;++r4){
          const int brow = rt*16 + lq*4 + r4;
          const float rg = sigm(ar_[rt][r4] + bir + bhr);
          const float zg = sigm(az_[rt][r4] + biz + bhz);
          const float ng = tanh_f((ani[rt][r4] + bin) + rg*(anh[rt][r4] + bhn));
          float h = h1s[rt][nt][r4];
          h = ng + zg*(h - ng);
          h1s[rt][nt][r4] = h;
          if (mylens[rt][r4] == t) outf[rt][nt][r4] = h;
          s1w[brow*LDS_STRIDE + jb] = f2bf(h);
        }
      }
    }
    // no barrier: next iteration's barrier A orders everything
  }
  __syncthreads();  // loop done; safe to reuse LDS for the head

  // ---- head: z = LeakyReLU(out_t @ w1^T + b1); enc = z @ w2^T + b2 ----
#pragma unroll
  for (int rt=0;rt<2;++rt)
#pragma unroll
    for (int nt=0;nt<2;++nt){
      const int jb = wid*32 + nt*16 + l15;
#pragma unroll
      for (int r4=0;r4<4;++r4)
        s0_lds[(rt*16+lq*4+r4)*LDS_STRIDE + jb] = f2bf(outf[rt][nt][r4]);
    }
  __syncthreads();

  {
    f4 az[2][2]; az[0][0]=zf; az[0][1]=zf; az[1][0]=zf; az[1][1]=zf;
#pragma unroll
    for (int kt=0;kt<8;++kt){
      bh8 a0 = *(const bh8*)(s0p + kt*32);
      bh8 a1 = *(const bh8*)(s0p + RT1 + kt*32);
#pragma unroll
      for (int nt=0;nt<2;++nt){
        bh8 b = packW1[(nt*8+kt)*64];
        az[nt][0] = mfma16(a0, b, az[nt][0]);
        az[nt][1] = mfma16(a1, b, az[nt][1]);
      }
    }
#pragma unroll
    for (int rt=0;rt<2;++rt)
#pragma unroll
      for (int nt=0;nt<2;++nt){
        const int jb = wid*32 + nt*16 + l15;
#pragma unroll
        for (int r4=0;r4<4;++r4){
          float v = az[nt][rt][r4] + b1s[jb];
          v = (v >= 0.f) ? v : 0.01f*v;     // LeakyReLU
          s1_lds[0][(rt*16+lq*4+r4)*LDS_STRIDE + jb] = f2bf(v);
        }
      }
  }
  __syncthreads();

  if (wid < 7){
    const short* zp = &s1_lds[0][afrag];
    f4 acc2[2]; acc2[0]=zf; acc2[1]=zf;
#pragma unroll
    for (int kt=0;kt<8;++kt){
      bh8 a0 = *(const bh8*)(zp + kt*32);
      bh8 a1 = *(const bh8*)(zp + RT1 + kt*32);
      bh8 b = packW2[kt*64];
      acc2[0] = mfma16(a0, b, acc2[0]);
      acc2[1] = mfma16(a1, b, acc2[1]);
    }
    const int n2 = wid*16 + l15;
    if (n2 < LOUT){
#pragma unroll
      for (int rt=0;rt<2;++rt)
#pragma unroll
        for (int r4=0;r4<4;++r4)
          out[(size_t)(b0 + rt*16 + lq*4 + r4)*LOUT + n2] = acc2[rt][r4] + b2s[n2];
    }
  }
}

extern "C" void kernel_launch(void* const* d_in, const int* in_sizes, int n_in,
                              void* d_out, int out_size, void* d_ws, size_t ws_size,
                              hipStream_t stream)
{
  const int*   tokens = (const int*)  d_in[0];
  const int*   lens   = (const int*)  d_in[1];
  const float* emb    = (const float*)d_in[2];
  const float* w_ih0  = (const float*)d_in[3];
  const float* w_hh0  = (const float*)d_in[4];
  const float* b_ih0  = (const float*)d_in[5];
  const float* b_hh0  = (const float*)d_in[6];
  const float* w_ih1  = (const float*)d_in[7];
  const float* w_hh1  = (const float*)d_in[8];
  const float* b_ih1  = (const float*)d_in[9];
  const float* b_hh1  = (const float*)d_in[10];
  const float* w1     = (const float*)d_in[11];
  const float* b1     = (const float*)d_in[12];
  const float* w2     = (const float*)d_in[13];
  const float* b2     = (const float*)d_in[14];

  float* E0   = (float*)d_ws;                                  // 196608 B
  short* pack = (short*)((char*)d_ws + 64*NG*sizeof(float));   // 1336 KiB packed bf16 tiles

  e0_kernel  <<<(64*NG + 255)/256,   256, 0, stream>>>(emb, w_ih0, b_ih0, E0);
  pack_kernel<<<(1336*64 + 255)/256, 256, 0, stream>>>(w_hh0, w_ih1, w_hh1, w1, w2, pack);
  rnn_main   <<<64, 512, 0, stream>>>(tokens, lens, E0, pack,
                                      b_hh0, b_ih1, b_hh1, b1, b2, (float*)d_out);
}